// Round 6
// baseline (156.293 us; speedup 1.0000x reference)
//
#include <hip/hip_runtime.h>
#include <math.h>

#define NFFT  1024
#define TIME_ 262144
#define NWIN  1021   // (262144 - 1024)/256 + 1
#define NPAIR 511    // pair p covers windows 2p, 2p+1
#define BATCH 32

typedef float fv4 __attribute__((ext_vector_type(4)));

__device__ __forceinline__ float2 cmul(float2 a, float2 b) {
    return make_float2(fmaf(a.x, b.x, -(a.y * b.y)),
                       fmaf(a.x, b.y,  (a.y * b.x)));
}
__device__ __forceinline__ float2 cconj(float2 a) { return make_float2(a.x, -a.y); }

// Forward 4-point DFT: X[k] = sum_n v[n] * (-i)^(n*k)
__device__ __forceinline__ void dft4(float2 v[4]) {
    float2 a = make_float2(v[0].x + v[2].x, v[0].y + v[2].y);
    float2 b = make_float2(v[0].x - v[2].x, v[0].y - v[2].y);
    float2 c = make_float2(v[1].x + v[3].x, v[1].y + v[3].y);
    float2 d = make_float2(v[1].x - v[3].x, v[1].y - v[3].y);
    v[0] = make_float2(a.x + c.x, a.y + c.y);
    v[2] = make_float2(a.x - c.x, a.y - c.y);
    v[1] = make_float2(b.x + d.y, b.y - d.x);   // b - i*d
    v[3] = make_float2(b.x - d.y, b.y + d.x);   // b + i*d
}

// Twiddle-fused DFT16: o[k] = sum_n (v[n] * w^n) * exp(-2pi i n k / 16),
// w = exp(i*ang). Carry 6 complex twiddles (12 VGPRs) instead of a 16-entry
// table (32 VGPRs); fold v[a+4k] * (w^a * W^k) into the first radix-4 pass.
__device__ __forceinline__ void dft16tw(const float2 v[16], float2 o[16],
                                        float2 w1, float2 w2, float2 w3,
                                        float2 w4, float2 w8, float2 w12) {
    const float C1 = 0.92387953251128675613f;   // cos(pi/8)
    const float S1 = 0.38268343236508977173f;   // sin(pi/8)
    const float R2 = 0.70710678118654752440f;   // sqrt(2)/2
    float2 c[4][4];                              // c[n1a][k1a]
    {   // column a = 0: twiddles are W^k directly
        float2 t[4] = { v[0], cmul(v[4], w4), cmul(v[8], w8), cmul(v[12], w12) };
        dft4(t);
#pragma unroll
        for (int k = 0; k < 4; ++k) c[0][k] = t[k];
    }
    const float2 wa3[3] = { w1, w2, w3 };
#pragma unroll
    for (int a = 1; a < 4; ++a) {
        const float2 wa = wa3[a - 1];
        const float2 p1 = cmul(wa, w4);
        const float2 p2 = cmul(wa, w8);
        const float2 p3 = cmul(wa, w12);
        float2 t[4] = { cmul(v[a], wa), cmul(v[a + 4], p1),
                        cmul(v[a + 8], p2), cmul(v[a + 12], p3) };
        dft4(t);
#pragma unroll
        for (int k = 0; k < 4; ++k) c[a][k] = t[k];
    }
    // c[n1a][k1a] *= W16^(n1a*k1a)
    c[1][1] = cmul(c[1][1], make_float2( C1, -S1));
    c[1][2] = cmul(c[1][2], make_float2( R2, -R2));
    c[1][3] = cmul(c[1][3], make_float2( S1, -C1));
    c[2][1] = cmul(c[2][1], make_float2( R2, -R2));
    c[2][2] = make_float2(c[2][2].y, -c[2][2].x);          // * W16^4 = -i
    c[2][3] = cmul(c[2][3], make_float2(-R2, -R2));
    c[3][1] = cmul(c[3][1], make_float2( S1, -C1));
    c[3][2] = cmul(c[3][2], make_float2(-R2, -R2));
    c[3][3] = cmul(c[3][3], make_float2(-C1,  S1));        // W16^9 = -W16^1
#pragma unroll
    for (int k1a = 0; k1a < 4; ++k1a) {
        float2 t[4] = { c[0][k1a], c[1][k1a], c[2][k1a], c[3][k1a] };
        dft4(t);
#pragma unroll
        for (int k1b = 0; k1b < 4; ++k1b) o[k1a + 4 * k1b] = t[k1b];
    }
}

// One 64-lane wave computes one window-pair via the two-for-one complex FFT:
//   s[n] = a[n] + i*b[n],  S = FFT1024(s),
//   Re A[k] = (S[k].x + S[-k].x)/2,  Re B[k] = (S[k].y + S[-k].y)/2.
// FFT1024 = radix-4 (regs) x DFT16tw (regs) x DFT16tw (regs), swizzled LDS
// exchanges, ZERO __syncthreads (wave-synchronous DS ordering, HW-validated
// rounds 1-5). n = n2 + 16*n1 + 256*n0, k = k0 + 4*k1 + 64*k2.
//
// R6: isolated nt-store check (R4 bundled it with a VGPR-regressing D=2
// pipeline; never cleanly read). Output stream (134 MB) is write-once ->
// bypass L2 so it doesn't evict the L2-resident input (32 MB ~ aggregate L2,
// 84 MB logical re-reads want L2 hits).
__global__ __launch_bounds__(256, 5) void StridedFourier_kernel(
    const float* __restrict__ x, float* __restrict__ out)
{
    __shared__ __align__(16) float2 lds[4][NFFT];

    const int tid  = threadIdx.x;
    const int lane = tid & 63;
    const int wid  = tid >> 6;

    // XCD-aware swizzle (bijective on 128).
    int bx = blockIdx.x;                 // 0..127
    bx = ((bx & 7) << 4) | (bx >> 3);
    const int p = bx * 4 + wid;          // window pair
    if (p >= NPAIR) return;              // one idle wave in one block column
    const int bat = blockIdx.y;
    const bool wbv = (2 * p + 1) < NWIN; // last pair is a singleton

    const float* src = x + (size_t)bat * TIME_ + (size_t)p * 512;
    float2* L = lds[wid];

    // ---- global load: 5 float4 per lane (20 samples), fully coalesced ----
    float Ls[20];
#pragma unroll
    for (int c = 0; c < 4; ++c) {
        float4 f = *(const float4*)(src + 4 * lane + 256 * c);
        Ls[4 * c + 0] = f.x; Ls[4 * c + 1] = f.y;
        Ls[4 * c + 2] = f.z; Ls[4 * c + 3] = f.w;
    }
    if (wbv) {
        float4 f = *(const float4*)(src + 4 * lane + 1024);
        Ls[16] = f.x; Ls[17] = f.y; Ls[18] = f.z; Ls[19] = f.w;
    } else {
        Ls[16] = Ls[17] = Ls[18] = Ls[19] = 0.0f;
    }

    // ---- stage 1: radix-4 over n0 (stride 256), write A[n2][k0][n1] ----
#pragma unroll
    for (int t = 0; t < 4; ++t) {
        float2 v[4];
#pragma unroll
        for (int n0 = 0; n0 < 4; ++n0)
            v[n0] = make_float2(Ls[4 * n0 + t], Ls[4 * n0 + 4 + t]);
        dft4(v);
        const int idx = 4 * lane + t;
        const int n2 = idx & 15, n1 = idx >> 4;
        const int wb = 64 * n2 + (n1 ^ ((n2 & 7) << 1));
#pragma unroll
        for (int k0 = 0; k0 < 4; ++k0)
            L[wb + 16 * k0] = v[k0];
    }

    // ---- exchange 1 read: lane owns (n2 = lane&15, k0 = lane>>4) ----
    const int n2r = lane & 15, k0r = lane >> 4;
    float2 Av[16];
    {
        const int rb = 64 * n2r + 16 * k0r;
        const int m  = (n2r & 7) << 1;
#pragma unroll
        for (int u = 0; u < 8; ++u) {
            float4 q = *(const float4*)&L[rb + ((2 * u) ^ m)];
            Av[2 * u]     = make_float2(q.x, q.y);
            Av[2 * u + 1] = make_float2(q.z, q.w);
        }
    }

    // ---- stage 2: twiddle W64^(n1*k0) fused into DFT16 over n1 -> k1 ----
    float2 Bq[16];
    {
        const float ang = -0.0981747704246810387f * (float)k0r;  // -2pi/64 * k0
        float s1, c1, s4, c4, s8, c8;
        __sincosf(ang, &s1, &c1);
        __sincosf(4.0f * ang, &s4, &c4);
        __sincosf(8.0f * ang, &s8, &c8);
        const float2 w1 = make_float2(c1, s1);
        const float2 w4 = make_float2(c4, s4);
        const float2 w8 = make_float2(c8, s8);
        dft16tw(Av, Bq, w1, cmul(w1, w1), cmul(w4, cconj(w1)),
                w4, w8, cmul(w8, w4));
    }

    // ---- exchange 2 write: B[n2][k0][k1] -> slot 16*(k0+4k1) + (n2 ^ swz) ----
#pragma unroll
    for (int k1 = 0; k1 < 16; ++k1) {
        const int lp = k0r + 4 * k1;
        L[16 * lp + (n2r ^ ((lp & 7) << 1))] = Bq[k1];
    }

    // ---- exchange 2 read: lane' = k0 + 4*k1 = lane, 16 consecutive n2 ----
    float2 Cv[16];
    {
        const int rb2 = 16 * lane;
        const int m2  = (lane & 7) << 1;
#pragma unroll
        for (int u = 0; u < 8; ++u) {
            float4 q = *(const float4*)&L[rb2 + ((2 * u) ^ m2)];
            Cv[2 * u]     = make_float2(q.x, q.y);
            Cv[2 * u + 1] = make_float2(q.z, q.w);
        }
    }

    // ---- stage 3: twiddle W1024^(n2*lane') fused into DFT16 over n2 -> k2 ----
    float2 Sv[16];                                     // Sv[k2] = S[lane + 64*k2]
    {
        const float ang = -0.00613592315154256491f * (float)lane; // -2pi/1024 * l'
        float s1, c1, s4, c4, s8, c8;
        __sincosf(ang, &s1, &c1);
        __sincosf(4.0f * ang, &s4, &c4);
        __sincosf(8.0f * ang, &s8, &c8);
        const float2 w1 = make_float2(c1, s1);
        const float2 w4 = make_float2(c4, s4);
        const float2 w8 = make_float2(c8, s8);
        dft16tw(Cv, Sv, w1, cmul(w1, w1), cmul(w4, cconj(w1)),
                w4, w8, cmul(w8, w4));
    }

    // ---- park S[k] (k = lane + 64*k2) into granule-swizzled layout ----
    // k -> j = lane&3, Lo = (lane>>2) + 16*(k2&3), g = k2>>2
    // slot = ((Lo&15)^j) + 16*(Lo>>4) + 64*j + 256*g
    {
        const int pb = ((lane >> 2) ^ (lane & 3)) + ((lane & 3) << 6);
#pragma unroll
        for (int k2 = 0; k2 < 16; ++k2)
            L[pb + 16 * (k2 & 3) + 256 * (k2 >> 2)] = Sv[k2];
    }

    // ---- epilogue: lane owns k = 4*lane + 256g + j; untangle + nt stores ----
    const int Ll  = lane & 15,      Lh  = lane >> 4;
    const int ML  = 63 - lane;
    const int MLl = ML & 15,        MLh = ML >> 4;
    const int Lm0 = (64 - lane) & 63;
    const int m0b = (Lm0 & 15) + 16 * (Lm0 >> 4);
    const long long cbase = ((long long)bat * NWIN + 2LL * p) * NFFT;
    float* oa = out + cbase + 4 * lane;
    float* ob = oa + NFFT;
#pragma unroll
    for (int g = 0; g < 4; ++g) {
        float2 So[4], Sm[4];
#pragma unroll
        for (int j = 0; j < 4; ++j)
            So[j] = L[(Ll ^ j) + 16 * Lh + 64 * j + 256 * g];
#pragma unroll
        for (int jp = 1; jp < 4; ++jp)      // Sm[4-jp] = mirror elem for j=4-jp
            Sm[4 - jp] = L[(MLl ^ jp) + 16 * MLh + 64 * jp + 256 * (3 - g)];
        const int gm0 = lane ? (3 - g) : ((4 - g) & 3);
        Sm[0] = L[m0b + 256 * gm0];

        fv4 av, bv;
        av.x = 0.5f * (So[0].x + Sm[0].x);  bv.x = 0.5f * (So[0].y + Sm[0].y);
        av.y = 0.5f * (So[1].x + Sm[1].x);  bv.y = 0.5f * (So[1].y + Sm[1].y);
        av.z = 0.5f * (So[2].x + Sm[2].x);  bv.z = 0.5f * (So[2].y + Sm[2].y);
        av.w = 0.5f * (So[3].x + Sm[3].x);  bv.w = 0.5f * (So[3].y + Sm[3].y);

        // 64 lanes x 16B contiguous = 1KB full-line wave store, L2-bypassed.
        __builtin_nontemporal_store(av, (fv4*)(oa + 256 * g));
        if (wbv) __builtin_nontemporal_store(bv, (fv4*)(ob + 256 * g));
    }
}

extern "C" void kernel_launch(void* const* d_in, const int* in_sizes, int n_in,
                              void* d_out, int out_size, void* d_ws, size_t ws_size,
                              hipStream_t stream) {
    const float* x = (const float*)d_in[0];
    float* out = (float*)d_out;
    dim3 grid(128, BATCH);               // 128 pair-blocks x 32 batches
    StridedFourier_kernel<<<grid, 256, 0, stream>>>(x, out);
}